// Round 4
// baseline (7822.528 us; speedup 1.0000x reference)
//
#include <hip/hip_runtime.h>

#define L_SEQ 512
#define BATCH 32
#define EMB 256
#define HID 256
#define G3 768
#define H2V 512
#define NFEAT 512
#define LOG2E 1.44269504f

typedef __bf16 bf16x8 __attribute__((ext_vector_type(8)));
typedef float f32x4 __attribute__((ext_vector_type(4)));
typedef unsigned short u16;
typedef unsigned int u32;

__device__ __forceinline__ u16 f2bf(float f) {
  u32 u = __builtin_bit_cast(u32, f);
  u32 r = (u + 0x7fffu + ((u >> 16) & 1u)) >> 16;
  return (u16)r;
}
__device__ __forceinline__ float bf2f(u16 b) {
  return __builtin_bit_cast(float, ((u32)b) << 16);
}
__device__ __forceinline__ float lo_bf(u32 u) {
  return __builtin_bit_cast(float, u << 16);
}
__device__ __forceinline__ float hi_bf(u32 u) {
  return __builtin_bit_cast(float, u & 0xFFFF0000u);
}

__global__ void k_cvt(const float* __restrict__ s, u16* __restrict__ d, int n, float scale) {
  int i = blockIdx.x * blockDim.x + threadIdx.x;
  int st = gridDim.x * blockDim.x;
  for (; i < n; i += st) d[i] = f2bf(s[i] * scale);
}

// whh: rows 0..511 (r,z) scaled log2e; rows 512..767 (n) scaled 2*log2e
__global__ void k_cvt_whh(const float* __restrict__ s, u16* __restrict__ d, int n) {
  int i = blockIdx.x * blockDim.x + threadIdx.x;
  int st = gridDim.x * blockDim.x;
  for (; i < n; i += st) {
    int row = i >> 8;                      // / HID
    if (row >= 768) row -= 768;
    float sc = (row >= 512) ? (2.0f * LOG2E) : LOG2E;
    d[i] = f2bf(s[i] * sc);
  }
}

__global__ void k_mkbias(const float* __restrict__ bih, const float* __restrict__ bhh,
                         float* __restrict__ cb) {
  int d = blockIdx.x, t = threadIdx.x;
  float v = bih[d * G3 + t];
  if (t < 512) v += bhh[d * G3 + t];     // bhh_r, bhh_z additive pre-sigmoid; bhh_n NOT foldable
  cb[d * G3 + t] = v;
}

__global__ __launch_bounds__(256) void k_embed(const int* __restrict__ ids,
    const float* __restrict__ emb, u16* __restrict__ x) {
  int blk = blockIdx.x;            // l*32 + b
  int l = blk >> 5, b = blk & 31;
  int row = ids[b * L_SEQ + l];
  x[(size_t)blk * EMB + threadIdx.x] = f2bf(emb[(size_t)row * EMB + threadIdx.x]);
}

// NT GEMM: C(M,N) = A(M,K)bf16 * B(N,K)bf16 (+bias). TRANS_B: B is (K,N) row-major.
// C_MODE: 0 = fp32, 1 = bf16, 2 = bf16 packed+scaled (log2e; n-gate 2*log2e) for k_gru.
template<int TRANS_B, int C_MODE, int ADD_BIAS>
__global__ __launch_bounds__(256) void k_gemm(
    const u16* __restrict__ A, const u16* __restrict__ B, void* __restrict__ Cv,
    const float* __restrict__ bias, int K, int lda, int ldb, int ldc,
    long sA, long sB, long sC, long sBias)
{
  __shared__ __align__(16) u16 As[64][40];
  __shared__ __align__(16) u16 Bs[64][40];
  const int z = blockIdx.z;
  A += z * sA; B += z * sB;
  const int m0 = blockIdx.y * 64, n0 = blockIdx.x * 64;
  const int t = threadIdx.x;
  const int wave = t >> 6, lane = t & 63, lhi = lane >> 4, llo = lane & 15;
  f32x4 acc[4] = {};
  const int ar = t >> 2, ak = (t & 3) * 8;
  const int bkr = t >> 3, bnn = (t & 7) * 8;
  for (int k0 = 0; k0 < K; k0 += 32) {
    uint4 av = *(const uint4*)(A + (long)(m0 + ar) * lda + k0 + ak);
    *(uint4*)&As[ar][ak] = av;
    if (!TRANS_B) {
      uint4 bv = *(const uint4*)(B + (long)(n0 + ar) * ldb + k0 + ak);
      *(uint4*)&Bs[ar][ak] = bv;
    } else {
      uint4 bv = *(const uint4*)(B + (long)(k0 + bkr) * ldb + n0 + bnn);
      u16 tmp[8];
      *(uint4*)tmp = bv;
      #pragma unroll
      for (int i = 0; i < 8; i++) Bs[bnn + i][bkr] = tmp[i];
    }
    __syncthreads();
    bf16x8 a = __builtin_bit_cast(bf16x8, *(const uint4*)&As[16 * wave + llo][lhi * 8]);
    #pragma unroll
    for (int j = 0; j < 4; j++) {
      bf16x8 b = __builtin_bit_cast(bf16x8, *(const uint4*)&Bs[16 * j + llo][lhi * 8]);
      acc[j] = __builtin_amdgcn_mfma_f32_16x16x32_bf16(a, b, acc[j], 0, 0, 0);
    }
    __syncthreads();
  }
  #pragma unroll
  for (int j = 0; j < 4; j++) {
    float bv = 0.f;
    if (ADD_BIAS) bv = bias[z * sBias + n0 + 16 * j + llo];
    #pragma unroll
    for (int r = 0; r < 4; r++) {
      long row = m0 + 16 * wave + lhi * 4 + r;
      long col = n0 + 16 * j + llo;
      float vv = acc[j][r] + bv;
      if (C_MODE == 2) {
        // pack for k_gru: dir z, l = row>>5, b = row&31, g = col>>8, cc = col&255
        int b = (int)(row & 31);
        long l = row >> 5;
        int cc = (int)(col & 255), g = (int)(col >> 8);
        vv *= (g == 2) ? (2.0f * LOG2E) : LOG2E;
        long idx = ((l * 2 + (b >> 4)) * 512 + (cc >> 5) * 64 + ((b & 15) >> 2) * 16 + (cc & 15)) * 24
                   + g * 8 + ((cc >> 4) & 1) * 4 + (b & 3);
        ((u16*)Cv)[z * sC + idx] = f2bf(vv);
      } else if (C_MODE == 1) {
        ((u16*)Cv)[z * sC + row * ldc + col] = f2bf(vv);
      } else {
        ((float*)Cv)[z * sC + row * ldc + col] = vv;
      }
    }
  }
}

// GRU recurrence, flag-synced (no per-step barrier). grid = 4: dir*2 + batch_half.
// 512 threads (8 waves). Wave w owns gh cols [32w,32w+32) for all 3 gates and thus
// produces h-chunk w. MFMA kt=c consumes exactly h-chunk c -> per-chunk hflag sync;
// each wave starts its MFMA phase at kt=w (own chunk, no wait), letting co-resident
// waves drift out of phase so gate-VALU overlaps MFMA. rflag protects h double-buffer
// (write of h(s+1) waits until all waves finished MFMA reads of step s-1).
__global__ __launch_bounds__(512, 2) void k_gru(
    const u16* __restrict__ whh, const float* __restrict__ bhh,
    const u16* __restrict__ gi, const float* __restrict__ h0,
    u16* __restrict__ out)
{
  const int dir = blockIdx.x >> 1;
  const int half = blockIdx.x & 1;
  const int b0 = half * 16;
  extern __shared__ __align__(16) char smem[];
  uint4 (*ldsB)[2][8][64] = (uint4(*)[2][8][64])smem;                 // 128 KB
  u16 (*h_lds)[16][264] = (u16(*)[16][264])(smem + 131072);           // 16896 B
  int* hflag = (int*)(smem + 131072 + 16896);                          // 8 ints
  int* rflag = hflag + 8;                                              // 8 ints
  const int t = threadIdx.x;
  const int w = t >> 6, lane = t & 63, lhi = lane >> 4, llo = lane & 15;
  const u16* whh_d = whh + dir * G3 * HID;

  // r,z tiles -> registers (tt = g*2+jj, g in {0,1})
  uint4 breg[4][8];
  #pragma unroll
  for (int tt = 0; tt < 4; tt++) {
    const int g = tt >> 1, jj = tt & 1;
    const u16* bp = whh_d + (size_t)(g * 256 + 32 * w + 16 * jj + llo) * HID + lhi * 8;
    #pragma unroll
    for (int kt = 0; kt < 8; kt++) breg[tt][kt] = *(const uint4*)(bp + kt * 32);
  }
  // n tiles -> LDS
  #pragma unroll
  for (int jj = 0; jj < 2; jj++) {
    const u16* bp = whh_d + (size_t)(512 + 32 * w + 16 * jj + llo) * HID + lhi * 8;
    #pragma unroll
    for (int kt = 0; kt < 8; kt++) ldsB[w][jj][kt][lane] = *(const uint4*)(bp + kt * 32);
  }
  // h0 -> h_lds[0] (A layout)
  {
    int m = t >> 5, c0 = (t & 31) * 8;
    const float* hp = h0 + (size_t)(dir * BATCH + b0 + m) * HID + c0;
    float4 f0 = *(const float4*)(hp);
    float4 f1 = *(const float4*)(hp + 4);
    u16 hh[8] = {f2bf(f0.x), f2bf(f0.y), f2bf(f0.z), f2bf(f0.w),
                 f2bf(f1.x), f2bf(f1.y), f2bf(f1.z), f2bf(f1.w)};
    *(uint4*)&h_lds[0][m][c0] = *(uint4*)hh;
  }
  // h_old in C-layout registers
  float hreg[8];
  #pragma unroll
  for (int jj = 0; jj < 2; jj++)
    #pragma unroll
    for (int r = 0; r < 4; r++)
      hreg[jj * 4 + r] = h0[(size_t)(dir * BATCH + b0 + lhi * 4 + r) * HID + 32 * w + 16 * jj + llo];
  const float bn0 = bhh[dir * G3 + 512 + 32 * w + llo] * (2.0f * LOG2E);
  const float bn1 = bhh[dir * G3 + 512 + 32 * w + 16 + llo] * (2.0f * LOG2E);

  if (t < 8) { hflag[t] = 0; rflag[t] = -1; }

  const int l0 = dir ? (L_SEQ - 1) : 0;
  const u16* gp = gi + (size_t)dir * 12582912 + (((size_t)l0 * 2 + half) * 512 + t) * 24;
  const long gdelta = dir ? -24576 : 24576;
  u16* ob = out + ((size_t)l0 * BATCH + b0 + lhi * 4) * H2V + dir * HID + 32 * w + llo;
  const long odelta = dir ? -(long)BATCH * H2V : (long)BATCH * H2V;
  __syncthreads();

  for (int s = 0; s < L_SEQ; s++) {
    const int rd = s & 1, wr = rd ^ 1;
    uint4 q0 = *(const uint4*)(gp);
    uint4 q1 = *(const uint4*)(gp + 8);
    uint4 q2 = *(const uint4*)(gp + 16);
    gp += gdelta;

    f32x4 acc[6];
    #pragma unroll
    for (int tt = 0; tt < 4; tt++) acc[tt] = (f32x4){0.f, 0.f, 0.f, 0.f};
    acc[4] = (f32x4){bn0, bn0, bn0, bn0};
    acc[5] = (f32x4){bn1, bn1, bn1, bn1};

    #pragma unroll
    for (int j = 0; j < 8; j++) {
      const int c = (w + j) & 7;
      if (j > 0) {
        while (__hip_atomic_load(&hflag[c], __ATOMIC_RELAXED, __HIP_MEMORY_SCOPE_WORKGROUP) < s) {}
      }
      bf16x8 a = __builtin_bit_cast(bf16x8, *(const uint4*)&h_lds[rd][llo][c * 32 + lhi * 8]);
      uint4 b4 = ldsB[w][0][c][lane];
      uint4 b5 = ldsB[w][1][c][lane];
      #pragma unroll
      for (int tt = 0; tt < 4; tt++)
        acc[tt] = __builtin_amdgcn_mfma_f32_16x16x32_bf16(
            a, __builtin_bit_cast(bf16x8, breg[tt][c]), acc[tt], 0, 0, 0);
      acc[4] = __builtin_amdgcn_mfma_f32_16x16x32_bf16(
          a, __builtin_bit_cast(bf16x8, b4), acc[4], 0, 0, 0);
      acc[5] = __builtin_amdgcn_mfma_f32_16x16x32_bf16(
          a, __builtin_bit_cast(bf16x8, b5), acc[5], 0, 0, 0);
    }
    // my MFMA reads of h(s) are done (consumed); publish for buffer-reuse protection
    __hip_atomic_store(&rflag[w], s, __ATOMIC_RELEASE, __HIP_MEMORY_SCOPE_WORKGROUP);

    u32 qw[12];
    *(uint4*)&qw[0] = q0; *(uint4*)&qw[4] = q1; *(uint4*)&qw[8] = q2;
    u16 hb[8];
    #pragma unroll
    for (int jj = 0; jj < 2; jj++) {
      #pragma unroll
      for (int rp = 0; rp < 2; rp++) {
        const u32 ur = qw[jj * 2 + rp], uz = qw[4 + jj * 2 + rp], un = qw[8 + jj * 2 + rp];
        #pragma unroll
        for (int e = 0; e < 2; e++) {
          const int r_ = rp * 2 + e, o = jj * 4 + r_;
          const float gr = e ? hi_bf(ur) : lo_bf(ur);
          const float gz = e ? hi_bf(uz) : lo_bf(uz);
          const float gn = e ? hi_bf(un) : lo_bf(un);
          float rr = __builtin_amdgcn_rcpf(1.f + __builtin_amdgcn_exp2f(-(gr + acc[jj][r_])));
          float zz = __builtin_amdgcn_rcpf(1.f + __builtin_amdgcn_exp2f(-(gz + acc[2 + jj][r_])));
          float p = gn + rr * acc[4 + jj][r_];          // pre-scaled by 2*log2e
          float nn = __builtin_amdgcn_rcpf(1.f + __builtin_amdgcn_exp2f(-p)) * 2.f - 1.f;
          float hv = nn + zz * (hreg[o] - nn);
          hreg[o] = hv;
          hb[o] = (u16)((__builtin_bit_cast(u32, hv) + 0x8000u) >> 16);
        }
      }
    }
    // global out stores (off LDS critical path)
    #pragma unroll
    for (int jj = 0; jj < 2; jj++)
      #pragma unroll
      for (int r_ = 0; r_ < 4; r_++)
        ob[r_ * H2V + jj * 16] = hb[jj * 4 + r_];
    ob += odelta;
    // wait until all waves finished reading h(s-1) from buf[wr]
    int mn;
    do {
      mn = 0x7fffffff;
      #pragma unroll
      for (int v = 0; v < 8; v++)
        mn = min(mn, __hip_atomic_load(&rflag[v], __ATOMIC_RELAXED, __HIP_MEMORY_SCOPE_WORKGROUP));
    } while (mn < s - 1);
    #pragma unroll
    for (int jj = 0; jj < 2; jj++)
      #pragma unroll
      for (int r_ = 0; r_ < 4; r_++)
        h_lds[wr][lhi * 4 + r_][32 * w + 16 * jj + llo] = hb[jj * 4 + r_];
    __hip_atomic_store(&hflag[w], s + 1, __ATOMIC_RELEASE, __HIP_MEMORY_SCOPE_WORKGROUP);
  }
}

__global__ __launch_bounds__(256) void k_softmax(float* __restrict__ e) {
  const int row = blockIdx.x * 4 + (threadIdx.x >> 6);
  const int lane = threadIdx.x & 63;
  float* p = e + (long)row * NFEAT;
  float v[8];
  #pragma unroll
  for (int i = 0; i < 8; i++) v[i] = p[lane + 64 * i];
  float mx = v[0];
  #pragma unroll
  for (int i = 1; i < 8; i++) mx = fmaxf(mx, v[i]);
  #pragma unroll
  for (int o = 1; o < 64; o <<= 1) mx = fmaxf(mx, __shfl_xor(mx, o, 64));
  float sum = 0.f;
  #pragma unroll
  for (int i = 0; i < 8; i++) { v[i] = __expf(v[i] - mx); sum += v[i]; }
  #pragma unroll
  for (int o = 1; o < 64; o <<= 1) sum += __shfl_xor(sum, o, 64);
  float inv = 1.0f / sum;
  #pragma unroll
  for (int i = 0; i < 8; i++) p[lane + 64 * i] = v[i] * inv;
}

// energy(L,B,F) probs -> attn_out (B,F,L) fp32 and Pb (B,F,L) bf16
__global__ __launch_bounds__(256) void k_transpose(const float* __restrict__ P,
    float* __restrict__ aout, u16* __restrict__ Pb)
{
  const int l0 = blockIdx.x * 64, f0 = blockIdx.y * 64, b = blockIdx.z;
  __shared__ float tile[64][65];
  const int t = threadIdx.x;
  const int ci = t & 63, q = t >> 6;
  #pragma unroll
  for (int s2 = 0; s2 < 16; s2++) {
    int li = q * 16 + s2;
    tile[li][ci] = P[((long)(l0 + li) * BATCH + b) * NFEAT + f0 + ci];
  }
  __syncthreads();
  #pragma unroll
  for (int s2 = 0; s2 < 16; s2++) {
    int f = q * 16 + s2;
    float val = tile[ci][f];
    long idx = ((long)b * NFEAT + f0 + f) * L_SEQ + l0 + ci;
    aout[idx] = val;
    Pb[idx] = f2bf(val);
  }
}

extern "C" void kernel_launch(void* const* d_in, const int* in_sizes, int n_in,
                              void* d_out, int out_size, void* d_ws, size_t ws_size,
                              hipStream_t stream)
{
  const int* ids      = (const int*)d_in[0];
  const float* hidden = (const float*)d_in[2];
  const float* fe     = (const float*)d_in[3];
  const float* emb    = (const float*)d_in[4];
  const float* wih0   = (const float*)d_in[5];
  const float* whh0   = (const float*)d_in[6];
  const float* bih0   = (const float*)d_in[7];
  const float* bhh0   = (const float*)d_in[8];
  const float* wih1   = (const float*)d_in[9];
  const float* whh1   = (const float*)d_in[10];
  const float* bih1   = (const float*)d_in[11];
  const float* bhh1   = (const float*)d_in[12];
  const float* law    = (const float*)d_in[13];
  const float* lab    = (const float*)d_in[14];
  const float* faw    = (const float*)d_in[15];
  const float* fab    = (const float*)d_in[16];
  const float* vmat   = (const float*)d_in[17];

  char* w = (char*)d_ws;
  size_t o = 0;
  auto alloc = [&](size_t elems, size_t esz) {
    void* p = w + o; o = (o + elems * esz + 255) & ~(size_t)255; return p;
  };
  u16* wih0b = (u16*)alloc((size_t)2 * 768 * 256, 2);
  u16* whh0b = (u16*)alloc((size_t)2 * 768 * 256, 2);
  u16* wih1b = (u16*)alloc((size_t)2 * 768 * 512, 2);
  u16* whh1b = (u16*)alloc((size_t)2 * 768 * 256, 2);
  u16* lawb  = (u16*)alloc((size_t)256 * 512, 2);
  u16* fawb  = (u16*)alloc((size_t)256 * 512, 2);
  u16* vb    = (u16*)alloc((size_t)128 * 256, 2);
  u16* feb   = (u16*)alloc((size_t)384 * 256, 2);
  u16* xb    = (u16*)alloc((size_t)16384 * 256, 2);
  u16* gi0   = (u16*)alloc((size_t)2 * 16384 * 768, 2);
  u16* out0  = (u16*)alloc((size_t)16384 * 512, 2);
  u16* gi1   = (u16*)alloc((size_t)2 * 16384 * 768, 2);
  u16* rnn   = (u16*)alloc((size_t)16384 * 512, 2);
  u16* wh    = (u16*)alloc((size_t)16384 * 256, 2);
  u16* wh2   = (u16*)alloc((size_t)16384 * 256, 2);
  float* energy = (float*)alloc((size_t)16384 * 512, 4);
  u16* Pb    = (u16*)alloc((size_t)16384 * 512, 2);
  float* cbias0 = (float*)alloc((size_t)2 * 768, 4);
  float* cbias1 = (float*)alloc((size_t)2 * 768, 4);

  k_cvt<<<96, 256, 0, stream>>>(wih0, wih0b, 2 * 768 * 256, 1.0f);
  k_cvt_whh<<<96, 256, 0, stream>>>(whh0, whh0b, 2 * 768 * 256);
  k_cvt<<<192, 256, 0, stream>>>(wih1, wih1b, 2 * 768 * 512, 1.0f);
  k_cvt_whh<<<96, 256, 0, stream>>>(whh1, whh1b, 2 * 768 * 256);
  k_cvt<<<32, 256, 0, stream>>>(law, lawb, 256 * 512, 1.0f);
  k_cvt<<<32, 256, 0, stream>>>(faw, fawb, 256 * 512, 1.0f);
  k_cvt<<<8, 256, 0, stream>>>(vmat, vb, 128 * 256, 1.0f);
  k_cvt<<<24, 256, 0, stream>>>(fe, feb, 384 * 256, 1.0f);
  k_mkbias<<<2, 768, 0, stream>>>(bih0, bhh0, cbias0);
  k_mkbias<<<2, 768, 0, stream>>>(bih1, bhh1, cbias1);
  k_embed<<<16384, 256, 0, stream>>>(ids, emb, xb);

  // gi0 = (x @ wih0^T + (bih0 + bhh0[r,z])) * scale, packed for k_gru
  k_gemm<0, 2, 1><<<dim3(12, 256, 2), 256, 0, stream>>>(xb, wih0b, gi0, cbias0,
      256, 256, 256, 768, 0L, 768L * 256, 12582912L, 768L);
  k_gru<<<4, 512, 148032, stream>>>(whh0b, bhh0, gi0, hidden, out0);

  // gi1 = (out0 @ wih1^T + (bih1 + bhh1[r,z])) * scale, packed
  k_gemm<0, 2, 1><<<dim3(12, 256, 2), 256, 0, stream>>>(out0, wih1b, gi1, cbias1,
      512, 512, 512, 768, 0L, 768L * 512, 12582912L, 768L);
  k_gru<<<4, 512, 148032, stream>>>(whh1b, bhh1, gi1, hidden + 2 * 32 * 256, rnn);

  // wh = rnn @ la_w^T + la_b (bf16), wh2 = rnn @ fa_w^T + fa_b (bf16)
  k_gemm<0, 1, 1><<<dim3(4, 256, 1), 256, 0, stream>>>(rnn, lawb, wh, lab,
      512, 512, 512, 256, 0L, 0L, 0L, 0L);
  k_gemm<0, 1, 1><<<dim3(4, 256, 1), 256, 0, stream>>>(rnn, fawb, wh2, fab,
      512, 512, 512, 256, 0L, 0L, 0L, 0L);
  // vwh -> energy[:,384:512] ; fwh -> energy[:,0:384]  (fp32)
  k_gemm<0, 0, 0><<<dim3(2, 256, 1), 256, 0, stream>>>(wh, vb, energy + 384, nullptr,
      256, 256, 256, 512, 0L, 0L, 0L, 0L);
  k_gemm<0, 0, 0><<<dim3(6, 256, 1), 256, 0, stream>>>(wh2, feb, energy, nullptr,
      256, 256, 256, 512, 0L, 0L, 0L, 0L);

  k_softmax<<<4096, 256, 0, stream>>>(energy);

  float* attn_out = (float*)d_out + (size_t)32 * 512 * 512;
  k_transpose<<<dim3(8, 8, 32), 256, 0, stream>>>(energy, attn_out, Pb);

  // context[b] = P[b](F,L) @ rnn(:,b,:)(L,2H)  -> d_out (B,F,2H) fp32
  k_gemm<1, 0, 0><<<dim3(8, 8, 32), 256, 0, stream>>>(Pb, rnn, (float*)d_out, nullptr,
      512, 512, 16384, 512, (long)512 * 512, 512L, (long)512 * 512, 0L);
}

// Round 5
// 2091.216 us; speedup vs baseline: 3.7407x; 3.7407x over previous
//
#include <hip/hip_runtime.h>

#define L_SEQ 512
#define BATCH 32
#define EMB 256
#define HID 256
#define G3 768
#define H2V 512
#define NFEAT 512
#define LOG2E 1.44269504f

typedef __bf16 bf16x8 __attribute__((ext_vector_type(8)));
typedef float f32x4 __attribute__((ext_vector_type(4)));
typedef unsigned short u16;
typedef unsigned int u32;

__device__ __forceinline__ u16 f2bf(float f) {
  u32 u = __builtin_bit_cast(u32, f);
  u32 r = (u + 0x7fffu + ((u >> 16) & 1u)) >> 16;
  return (u16)r;
}
__device__ __forceinline__ float bf2f(u16 b) {
  return __builtin_bit_cast(float, ((u32)b) << 16);
}
__device__ __forceinline__ float lo_bf(u32 u) {
  return __builtin_bit_cast(float, u << 16);
}
__device__ __forceinline__ float hi_bf(u32 u) {
  return __builtin_bit_cast(float, u & 0xFFFF0000u);
}

__global__ void k_cvt(const float* __restrict__ s, u16* __restrict__ d, int n, float scale) {
  int i = blockIdx.x * blockDim.x + threadIdx.x;
  int st = gridDim.x * blockDim.x;
  for (; i < n; i += st) d[i] = f2bf(s[i] * scale);
}

// whh: rows 0..511 (r,z) scaled log2e; rows 512..767 (n) scaled 2*log2e
__global__ void k_cvt_whh(const float* __restrict__ s, u16* __restrict__ d, int n) {
  int i = blockIdx.x * blockDim.x + threadIdx.x;
  int st = gridDim.x * blockDim.x;
  for (; i < n; i += st) {
    int row = i >> 8;                      // / HID
    if (row >= 768) row -= 768;
    float sc = (row >= 512) ? (2.0f * LOG2E) : LOG2E;
    d[i] = f2bf(s[i] * sc);
  }
}

__global__ void k_mkbias(const float* __restrict__ bih, const float* __restrict__ bhh,
                         float* __restrict__ cb) {
  int d = blockIdx.x, t = threadIdx.x;
  float v = bih[d * G3 + t];
  if (t < 512) v += bhh[d * G3 + t];     // bhh_r, bhh_z additive pre-sigmoid; bhh_n NOT foldable
  cb[d * G3 + t] = v;
}

__global__ __launch_bounds__(256) void k_embed(const int* __restrict__ ids,
    const float* __restrict__ emb, u16* __restrict__ x) {
  int blk = blockIdx.x;            // l*32 + b
  int l = blk >> 5, b = blk & 31;
  int row = ids[b * L_SEQ + l];
  x[(size_t)blk * EMB + threadIdx.x] = f2bf(emb[(size_t)row * EMB + threadIdx.x]);
}

// NT GEMM: C(M,N) = A(M,K)bf16 * B(N,K)bf16 (+bias). TRANS_B: B is (K,N) row-major.
// C_MODE: 0 = fp32, 1 = bf16, 2 = bf16 packed+scaled (log2e; n-gate 2*log2e) for k_gru.
template<int TRANS_B, int C_MODE, int ADD_BIAS>
__global__ __launch_bounds__(256) void k_gemm(
    const u16* __restrict__ A, const u16* __restrict__ B, void* __restrict__ Cv,
    const float* __restrict__ bias, int K, int lda, int ldb, int ldc,
    long sA, long sB, long sC, long sBias)
{
  __shared__ __align__(16) u16 As[64][40];
  __shared__ __align__(16) u16 Bs[64][40];
  const int z = blockIdx.z;
  A += z * sA; B += z * sB;
  const int m0 = blockIdx.y * 64, n0 = blockIdx.x * 64;
  const int t = threadIdx.x;
  const int wave = t >> 6, lane = t & 63, lhi = lane >> 4, llo = lane & 15;
  f32x4 acc[4] = {};
  const int ar = t >> 2, ak = (t & 3) * 8;
  const int bkr = t >> 3, bnn = (t & 7) * 8;
  for (int k0 = 0; k0 < K; k0 += 32) {
    uint4 av = *(const uint4*)(A + (long)(m0 + ar) * lda + k0 + ak);
    *(uint4*)&As[ar][ak] = av;
    if (!TRANS_B) {
      uint4 bv = *(const uint4*)(B + (long)(n0 + ar) * ldb + k0 + ak);
      *(uint4*)&Bs[ar][ak] = bv;
    } else {
      uint4 bv = *(const uint4*)(B + (long)(k0 + bkr) * ldb + n0 + bnn);
      u16 tmp[8];
      *(uint4*)tmp = bv;
      #pragma unroll
      for (int i = 0; i < 8; i++) Bs[bnn + i][bkr] = tmp[i];
    }
    __syncthreads();
    bf16x8 a = __builtin_bit_cast(bf16x8, *(const uint4*)&As[16 * wave + llo][lhi * 8]);
    #pragma unroll
    for (int j = 0; j < 4; j++) {
      bf16x8 b = __builtin_bit_cast(bf16x8, *(const uint4*)&Bs[16 * j + llo][lhi * 8]);
      acc[j] = __builtin_amdgcn_mfma_f32_16x16x32_bf16(a, b, acc[j], 0, 0, 0);
    }
    __syncthreads();
  }
  #pragma unroll
  for (int j = 0; j < 4; j++) {
    float bv = 0.f;
    if (ADD_BIAS) bv = bias[z * sBias + n0 + 16 * j + llo];
    #pragma unroll
    for (int r = 0; r < 4; r++) {
      long row = m0 + 16 * wave + lhi * 4 + r;
      long col = n0 + 16 * j + llo;
      float vv = acc[j][r] + bv;
      if (C_MODE == 2) {
        // pack for k_gru: dir z, l = row>>5, b = row&31, g = col>>8, cc = col&255
        int b = (int)(row & 31);
        long l = row >> 5;
        int cc = (int)(col & 255), g = (int)(col >> 8);
        vv *= (g == 2) ? (2.0f * LOG2E) : LOG2E;
        long idx = ((l * 2 + (b >> 4)) * 512 + (cc >> 5) * 64 + ((b & 15) >> 2) * 16 + (cc & 15)) * 24
                   + g * 8 + ((cc >> 4) & 1) * 4 + (b & 3);
        ((u16*)Cv)[z * sC + idx] = f2bf(vv);
      } else if (C_MODE == 1) {
        ((u16*)Cv)[z * sC + row * ldc + col] = f2bf(vv);
      } else {
        ((float*)Cv)[z * sC + row * ldc + col] = vv;
      }
    }
  }
}

// GRU recurrence, flag-synced, DATA-rotated weights (static register indexing).
// grid = 4: dir*2 + batch_half. 512 threads (8 waves). Wave w owns gh cols
// [32w,32w+32) for all 3 gates -> produces h-chunk w. Wave w's MFMA visits
// h-chunks in order w, w+1, ..: chunk j in the unrolled loop is h-chunk (w+j)&7,
// and breg[tt][j] holds the weight k-slice for that chunk (rotation applied at
// PRELOAD, so all register indices are compile-time). Own chunk (j=0) needs no
// wait; others poll hflag. Drift bounded to 1 step by hflag => double buffer
// suffices, no reader-flag scan needed.
__global__ __launch_bounds__(512, 2) void k_gru(
    const u16* __restrict__ whh, const float* __restrict__ bhh,
    const u16* __restrict__ gi, const float* __restrict__ h0,
    u16* __restrict__ out)
{
  const int dir = blockIdx.x >> 1;
  const int half = blockIdx.x & 1;
  const int b0 = half * 16;
  extern __shared__ __align__(16) char smem[];
  uint4 (*ldsB)[2][8][64] = (uint4(*)[2][8][64])smem;                 // 128 KB
  u16 (*h_lds)[16][264] = (u16(*)[16][264])(smem + 131072);           // 16896 B
  int* hflag = (int*)(smem + 131072 + 16896);                          // 8 ints
  const int t = threadIdx.x;
  const int w = t >> 6, lane = t & 63, lhi = lane >> 4, llo = lane & 15;
  const u16* whh_d = whh + dir * G3 * HID;

  // r,z tiles -> registers, k-chunks ROTATED: breg[tt][j] = k-chunk (w+j)&7
  uint4 breg[4][8];
  #pragma unroll
  for (int tt = 0; tt < 4; tt++) {
    const int g = tt >> 1, jj = tt & 1;
    const u16* bp = whh_d + (size_t)(g * 256 + 32 * w + 16 * jj + llo) * HID + lhi * 8;
    #pragma unroll
    for (int j = 0; j < 8; j++) {
      const int kc = (w + j) & 7;
      breg[tt][j] = *(const uint4*)(bp + kc * 32);
    }
  }
  // n tiles -> LDS, same rotation: ldsB[w][jj][j][lane] = k-chunk (w+j)&7
  #pragma unroll
  for (int jj = 0; jj < 2; jj++) {
    const u16* bp = whh_d + (size_t)(512 + 32 * w + 16 * jj + llo) * HID + lhi * 8;
    #pragma unroll
    for (int j = 0; j < 8; j++) {
      const int kc = (w + j) & 7;
      ldsB[w][jj][j][lane] = *(const uint4*)(bp + kc * 32);
    }
  }
  // h0 -> h_lds[0] (A layout)
  {
    int m = t >> 5, c0 = (t & 31) * 8;
    const float* hp = h0 + (size_t)(dir * BATCH + b0 + m) * HID + c0;
    float4 f0 = *(const float4*)(hp);
    float4 f1 = *(const float4*)(hp + 4);
    u16 hh[8] = {f2bf(f0.x), f2bf(f0.y), f2bf(f0.z), f2bf(f0.w),
                 f2bf(f1.x), f2bf(f1.y), f2bf(f1.z), f2bf(f1.w)};
    *(uint4*)&h_lds[0][m][c0] = *(uint4*)hh;
  }
  // h_old in C-layout registers
  float hreg[8];
  #pragma unroll
  for (int jj = 0; jj < 2; jj++)
    #pragma unroll
    for (int r = 0; r < 4; r++)
      hreg[jj * 4 + r] = h0[(size_t)(dir * BATCH + b0 + lhi * 4 + r) * HID + 32 * w + 16 * jj + llo];
  const float bn0 = bhh[dir * G3 + 512 + 32 * w + llo] * (2.0f * LOG2E);
  const float bn1 = bhh[dir * G3 + 512 + 32 * w + 16 + llo] * (2.0f * LOG2E);

  if (t < 8) hflag[t] = 0;    // hflag[c] = v  <=>  h(v) chunk c readable

  const int l0 = dir ? (L_SEQ - 1) : 0;
  const u16* gp = gi + (size_t)dir * 12582912 + (((size_t)l0 * 2 + half) * 512 + t) * 24;
  const long gdelta = dir ? -24576 : 24576;
  u16* ob = out + ((size_t)l0 * BATCH + b0 + lhi * 4) * H2V + dir * HID + 32 * w + llo;
  const long odelta = dir ? -(long)BATCH * H2V : (long)BATCH * H2V;
  __syncthreads();

  for (int s = 0; s < L_SEQ; s++) {
    const int rd = s & 1, wr = rd ^ 1;
    uint4 q0 = *(const uint4*)(gp);
    uint4 q1 = *(const uint4*)(gp + 8);
    uint4 q2 = *(const uint4*)(gp + 16);
    gp += gdelta;

    f32x4 acc[6];
    #pragma unroll
    for (int tt = 0; tt < 4; tt++) acc[tt] = (f32x4){0.f, 0.f, 0.f, 0.f};
    acc[4] = (f32x4){bn0, bn0, bn0, bn0};
    acc[5] = (f32x4){bn1, bn1, bn1, bn1};

    #pragma unroll
    for (int j = 0; j < 8; j++) {       // j static; h-chunk c runtime (memory only)
      const int c = (w + j) & 7;
      if (j > 0) {
        while (__hip_atomic_load(&hflag[c], __ATOMIC_ACQUIRE, __HIP_MEMORY_SCOPE_WORKGROUP) < s) {}
      }
      bf16x8 a = __builtin_bit_cast(bf16x8, *(const uint4*)&h_lds[rd][llo][c * 32 + lhi * 8]);
      uint4 b4 = ldsB[w][0][j][lane];
      uint4 b5 = ldsB[w][1][j][lane];
      #pragma unroll
      for (int tt = 0; tt < 4; tt++)
        acc[tt] = __builtin_amdgcn_mfma_f32_16x16x32_bf16(
            a, __builtin_bit_cast(bf16x8, breg[tt][j]), acc[tt], 0, 0, 0);
      acc[4] = __builtin_amdgcn_mfma_f32_16x16x32_bf16(
          a, __builtin_bit_cast(bf16x8, b4), acc[4], 0, 0, 0);
      acc[5] = __builtin_amdgcn_mfma_f32_16x16x32_bf16(
          a, __builtin_bit_cast(bf16x8, b5), acc[5], 0, 0, 0);
    }

    u32 qw[12];
    *(uint4*)&qw[0] = q0; *(uint4*)&qw[4] = q1; *(uint4*)&qw[8] = q2;
    u16 hb[8];
    #pragma unroll
    for (int jj = 0; jj < 2; jj++) {
      #pragma unroll
      for (int rp = 0; rp < 2; rp++) {
        const u32 ur = qw[jj * 2 + rp], uz = qw[4 + jj * 2 + rp], un = qw[8 + jj * 2 + rp];
        #pragma unroll
        for (int e = 0; e < 2; e++) {
          const int r_ = rp * 2 + e, o = jj * 4 + r_;
          const float gr = e ? hi_bf(ur) : lo_bf(ur);
          const float gz = e ? hi_bf(uz) : lo_bf(uz);
          const float gn = e ? hi_bf(un) : lo_bf(un);
          float rr = __builtin_amdgcn_rcpf(1.f + __builtin_amdgcn_exp2f(-(gr + acc[jj][r_])));
          float zz = __builtin_amdgcn_rcpf(1.f + __builtin_amdgcn_exp2f(-(gz + acc[2 + jj][r_])));
          float q = __builtin_amdgcn_rcpf(1.f + __builtin_amdgcn_exp2f(-(gn + rr * acc[4 + jj][r_])));
          float u = __builtin_fmaf(2.f, q, -1.f);            // tanh
          float hv = __builtin_fmaf(zz, hreg[o] - u, u);
          hreg[o] = hv;
          hb[o] = (u16)((__builtin_bit_cast(u32, hv) + 0x8000u) >> 16);
        }
      }
    }
    // h chunk w -> LDS, then release-publish, then global stores (off critical path)
    #pragma unroll
    for (int jj = 0; jj < 2; jj++)
      #pragma unroll
      for (int r_ = 0; r_ < 4; r_++)
        h_lds[wr][lhi * 4 + r_][32 * w + 16 * jj + llo] = hb[jj * 4 + r_];
    if (lane == 0)
      __hip_atomic_store(&hflag[w], s + 1, __ATOMIC_RELEASE, __HIP_MEMORY_SCOPE_WORKGROUP);
    #pragma unroll
    for (int jj = 0; jj < 2; jj++)
      #pragma unroll
      for (int r_ = 0; r_ < 4; r_++)
        ob[r_ * H2V + jj * 16] = hb[jj * 4 + r_];
    ob += odelta;
  }
}

__global__ __launch_bounds__(256) void k_softmax(float* __restrict__ e) {
  const int row = blockIdx.x * 4 + (threadIdx.x >> 6);
  const int lane = threadIdx.x & 63;
  float* p = e + (long)row * NFEAT;
  float v[8];
  #pragma unroll
  for (int i = 0; i < 8; i++) v[i] = p[lane + 64 * i];
  float mx = v[0];
  #pragma unroll
  for (int i = 1; i < 8; i++) mx = fmaxf(mx, v[i]);
  #pragma unroll
  for (int o = 1; o < 64; o <<= 1) mx = fmaxf(mx, __shfl_xor(mx, o, 64));
  float sum = 0.f;
  #pragma unroll
  for (int i = 0; i < 8; i++) { v[i] = __expf(v[i] - mx); sum += v[i]; }
  #pragma unroll
  for (int o = 1; o < 64; o <<= 1) sum += __shfl_xor(sum, o, 64);
  float inv = 1.0f / sum;
  #pragma unroll
  for (int i = 0; i < 8; i++) p[lane + 64 * i] = v[i] * inv;
}

// energy(L,B,F) probs -> attn_out (B,F,L) fp32 and Pb (B,F,L) bf16
__global__ __launch_bounds__(256) void k_transpose(const float* __restrict__ P,
    float* __restrict__ aout, u16* __restrict__ Pb)
{
  const int l0 = blockIdx.x * 64, f0 = blockIdx.y * 64, b = blockIdx.z;
  __shared__ float tile[64][65];
  const int t = threadIdx.x;
  const int ci = t & 63, q = t >> 6;
  #pragma unroll
  for (int s2 = 0; s2 < 16; s2++) {
    int li = q * 16 + s2;
    tile[li][ci] = P[((long)(l0 + li) * BATCH + b) * NFEAT + f0 + ci];
  }
  __syncthreads();
  #pragma unroll
  for (int s2 = 0; s2 < 16; s2++) {
    int f = q * 16 + s2;
    float val = tile[ci][f];
    long idx = ((long)b * NFEAT + f0 + f) * L_SEQ + l0 + ci;
    aout[idx] = val;
    Pb[idx] = f2bf(val);
  }
}

extern "C" void kernel_launch(void* const* d_in, const int* in_sizes, int n_in,
                              void* d_out, int out_size, void* d_ws, size_t ws_size,
                              hipStream_t stream)
{
  const int* ids      = (const int*)d_in[0];
  const float* hidden = (const float*)d_in[2];
  const float* fe     = (const float*)d_in[3];
  const float* emb    = (const float*)d_in[4];
  const float* wih0   = (const float*)d_in[5];
  const float* whh0   = (const float*)d_in[6];
  const float* bih0   = (const float*)d_in[7];
  const float* bhh0   = (const float*)d_in[8];
  const float* wih1   = (const float*)d_in[9];
  const float* whh1   = (const float*)d_in[10];
  const float* bih1   = (const float*)d_in[11];
  const float* bhh1   = (const float*)d_in[12];
  const float* law    = (const float*)d_in[13];
  const float* lab    = (const float*)d_in[14];
  const float* faw    = (const float*)d_in[15];
  const float* fab    = (const float*)d_in[16];
  const float* vmat   = (const float*)d_in[17];

  char* w = (char*)d_ws;
  size_t o = 0;
  auto alloc = [&](size_t elems, size_t esz) {
    void* p = w + o; o = (o + elems * esz + 255) & ~(size_t)255; return p;
  };
  u16* wih0b = (u16*)alloc((size_t)2 * 768 * 256, 2);
  u16* whh0b = (u16*)alloc((size_t)2 * 768 * 256, 2);
  u16* wih1b = (u16*)alloc((size_t)2 * 768 * 512, 2);
  u16* whh1b = (u16*)alloc((size_t)2 * 768 * 256, 2);
  u16* lawb  = (u16*)alloc((size_t)256 * 512, 2);
  u16* fawb  = (u16*)alloc((size_t)256 * 512, 2);
  u16* vb    = (u16*)alloc((size_t)128 * 256, 2);
  u16* feb   = (u16*)alloc((size_t)384 * 256, 2);
  u16* xb    = (u16*)alloc((size_t)16384 * 256, 2);
  u16* gi0   = (u16*)alloc((size_t)2 * 16384 * 768, 2);
  u16* out0  = (u16*)alloc((size_t)16384 * 512, 2);
  u16* gi1   = (u16*)alloc((size_t)2 * 16384 * 768, 2);
  u16* rnn   = (u16*)alloc((size_t)16384 * 512, 2);
  u16* wh    = (u16*)alloc((size_t)16384 * 256, 2);
  u16* wh2   = (u16*)alloc((size_t)16384 * 256, 2);
  float* energy = (float*)alloc((size_t)16384 * 512, 4);
  u16* Pb    = (u16*)alloc((size_t)16384 * 512, 2);
  float* cbias0 = (float*)alloc((size_t)2 * 768, 4);
  float* cbias1 = (float*)alloc((size_t)2 * 768, 4);

  k_cvt<<<96, 256, 0, stream>>>(wih0, wih0b, 2 * 768 * 256, 1.0f);
  k_cvt_whh<<<96, 256, 0, stream>>>(whh0, whh0b, 2 * 768 * 256);
  k_cvt<<<192, 256, 0, stream>>>(wih1, wih1b, 2 * 768 * 512, 1.0f);
  k_cvt_whh<<<96, 256, 0, stream>>>(whh1, whh1b, 2 * 768 * 256);
  k_cvt<<<32, 256, 0, stream>>>(law, lawb, 256 * 512, 1.0f);
  k_cvt<<<32, 256, 0, stream>>>(faw, fawb, 256 * 512, 1.0f);
  k_cvt<<<8, 256, 0, stream>>>(vmat, vb, 128 * 256, 1.0f);
  k_cvt<<<24, 256, 0, stream>>>(fe, feb, 384 * 256, 1.0f);
  k_mkbias<<<2, 768, 0, stream>>>(bih0, bhh0, cbias0);
  k_mkbias<<<2, 768, 0, stream>>>(bih1, bhh1, cbias1);
  k_embed<<<16384, 256, 0, stream>>>(ids, emb, xb);

  // gi0 = (x @ wih0^T + (bih0 + bhh0[r,z])) * scale, packed for k_gru
  k_gemm<0, 2, 1><<<dim3(12, 256, 2), 256, 0, stream>>>(xb, wih0b, gi0, cbias0,
      256, 256, 256, 768, 0L, 768L * 256, 12582912L, 768L);
  k_gru<<<4, 512, 148000, stream>>>(whh0b, bhh0, gi0, hidden, out0);

  // gi1 = (out0 @ wih1^T + (bih1 + bhh1[r,z])) * scale, packed
  k_gemm<0, 2, 1><<<dim3(12, 256, 2), 256, 0, stream>>>(out0, wih1b, gi1, cbias1,
      512, 512, 512, 768, 0L, 768L * 512, 12582912L, 768L);
  k_gru<<<4, 512, 148000, stream>>>(whh1b, bhh1, gi1, hidden + 2 * 32 * 256, rnn);

  // wh = rnn @ la_w^T + la_b (bf16), wh2 = rnn @ fa_w^T + fa_b (bf16)
  k_gemm<0, 1, 1><<<dim3(4, 256, 1), 256, 0, stream>>>(rnn, lawb, wh, lab,
      512, 512, 512, 256, 0L, 0L, 0L, 0L);
  k_gemm<0, 1, 1><<<dim3(4, 256, 1), 256, 0, stream>>>(rnn, fawb, wh2, fab,
      512, 512, 512, 256, 0L, 0L, 0L, 0L);
  // vwh -> energy[:,384:512] ; fwh -> energy[:,0:384]  (fp32)
  k_gemm<0, 0, 0><<<dim3(2, 256, 1), 256, 0, stream>>>(wh, vb, energy + 384, nullptr,
      256, 256, 256, 512, 0L, 0L, 0L, 0L);
  k_gemm<0, 0, 0><<<dim3(6, 256, 1), 256, 0, stream>>>(wh2, feb, energy, nullptr,
      256, 256, 256, 512, 0L, 0L, 0L, 0L);

  k_softmax<<<4096, 256, 0, stream>>>(energy);

  float* attn_out = (float*)d_out + (size_t)32 * 512 * 512;
  k_transpose<<<dim3(8, 8, 32), 256, 0, stream>>>(energy, attn_out, Pb);

  // context[b] = P[b](F,L) @ rnn(:,b,:)(L,2H)  -> d_out (B,F,2H) fp32
  k_gemm<1, 0, 0><<<dim3(8, 8, 32), 256, 0, stream>>>(Pb, rnn, (float*)d_out, nullptr,
      512, 512, 16384, 512, (long)512 * 512, 512L, (long)512 * 512, 0L);
}